// Round 10
// baseline (239.503 us; speedup 1.0000x reference)
//
#include <hip/hip_runtime.h>
#include <hip/hip_bf16.h>

#define INF 128
#define OUTF 64
#define ALPHA 0.2f
#define EPSV 1e-6f

typedef __bf16 bf16x8 __attribute__((ext_vector_type(8)));
typedef float  f32x4  __attribute__((ext_vector_type(4)));

static __device__ __forceinline__ unsigned short bf16bits(float f) {
    __hip_bfloat16 b = __float2bfloat16(f);
    return *(unsigned short*)&b;
}

// ---------------------------------------------------------------------------
// k_prep0: zero deg[N] AND precompute Wfc hi/lo bf16 split (row-major
// [64][128]) once, instead of per-wave in k_fc. Replaces the deg memset.
// ---------------------------------------------------------------------------
__global__ __launch_bounds__(256)
void k_prep0(const float* __restrict__ Wfc, __bf16* __restrict__ WfcHi,
             __bf16* __restrict__ WfcLo, int* __restrict__ deg, int N)
{
    int gid = blockIdx.x * 256 + threadIdx.x;
    if (gid < N) deg[gid] = 0;
    if (gid < OUTF * INF) {
        float f = Wfc[gid];
        __bf16 hi = (__bf16)f;
        WfcHi[gid] = hi;
        WfcLo[gid] = (__bf16)(f - (float)hi);
    }
}

// ---------------------------------------------------------------------------
// k_fc (MFMA): Wh = h @ Wfc^T via 16x16x32 bf16 MFMA, 3-term bf16 split.
// B-fragments loaded pre-split (bf16, half the bytes, zero cvt VALU).
// Whb stored in PERMUTED interleaved layout: node block = 256B =
// [b0:16 chunks][b1:16 chunks]; chunk q of a row = cols {q,16+q,32+q,48+q},
// written as ONE uint2 (4 bf16) per row per lane -> 4 coalesced 8B stores
// instead of 16 scalar 2B stores. s1/s2 stored interleaved per node
// (s1i[2n+b]) for the scatter's float2 reads.
// ---------------------------------------------------------------------------
__global__ __launch_bounds__(256, 2)
void k_fc(const float* __restrict__ h, const __bf16* __restrict__ WfcHi,
          const __bf16* __restrict__ WfcLo, const float* __restrict__ Wattn,
          uint2* __restrict__ Whb, float* __restrict__ s1i,
          float* __restrict__ s2i, int BN, int N)
{
    int lane = threadIdx.x & 63;
    int wv   = blockIdx.x * 4 + (threadIdx.x >> 6);
    int base = wv * 16;
    if (base >= BN) return;
    int q = lane & 15, quad = lane >> 4;

    // B fragments: row t*16+q, k = kb*32 + quad*8 + j  (16B aligned vector loads)
    bf16x8 bhi[16], blo[16];
#pragma unroll
    for (int kb = 0; kb < 4; ++kb) {
#pragma unroll
        for (int t = 0; t < 4; ++t) {
            size_t off = (size_t)(t * 16 + q) * INF + kb * 32 + quad * 8;
            bhi[kb * 4 + t] = *(const bf16x8*)(WfcHi + off);
            blo[kb * 4 + t] = *(const bf16x8*)(WfcLo + off);
        }
    }

    f32x4 acc[4];
#pragma unroll
    for (int t = 0; t < 4; ++t) acc[t] = (f32x4){0.f, 0.f, 0.f, 0.f};

    const float* hrow = h + (size_t)(base + q) * INF + quad * 8;
#pragma unroll
    for (int kb = 0; kb < 4; ++kb) {
        float4 h0 = *(const float4*)(hrow + kb * 32);
        float4 h1 = *(const float4*)(hrow + kb * 32 + 4);
        float hv8[8] = {h0.x, h0.y, h0.z, h0.w, h1.x, h1.y, h1.z, h1.w};
        bf16x8 ahi, alo;
#pragma unroll
        for (int j = 0; j < 8; ++j) {
            ahi[j] = (__bf16)hv8[j];
            alo[j] = (__bf16)(hv8[j] - (float)ahi[j]);
        }
#pragma unroll
        for (int t = 0; t < 4; ++t) {
            acc[t] = __builtin_amdgcn_mfma_f32_16x16x32_bf16(ahi, bhi[kb * 4 + t], acc[t], 0, 0, 0);
            acc[t] = __builtin_amdgcn_mfma_f32_16x16x32_bf16(ahi, blo[kb * 4 + t], acc[t], 0, 0, 0);
            acc[t] = __builtin_amdgcn_mfma_f32_16x16x32_bf16(alo, bhi[kb * 4 + t], acc[t], 0, 0, 0);
        }
    }

    // store Whb permuted: row rr -> (b = rr>=N, n = rr-b*N);
    // uint2 index = (n*2+b)*16 + q, payload = cols {q,16+q} | {32+q,48+q}
#pragma unroll
    for (int r = 0; r < 4; ++r) {
        int rr = base + quad * 4 + r;
        int b = (rr >= N) ? 1 : 0;
        int n = rr - b * N;
        unsigned lo = (unsigned)bf16bits(acc[0][r]) | ((unsigned)bf16bits(acc[1][r]) << 16);
        unsigned hi = (unsigned)bf16bits(acc[2][r]) | ((unsigned)bf16bits(acc[3][r]) << 16);
        Whb[((size_t)n * 2 + b) * 16 + q] = make_uint2(lo, hi);
    }

    // fused s1/s2 (interleaved per node: s1i[2n+b])
    float aS[4], aD[4];
#pragma unroll
    for (int t = 0; t < 4; ++t) {
        aS[t] = Wattn[t * 16 + q];
        aD[t] = Wattn[OUTF + t * 16 + q];
    }
    float t1[4], t2[4];
#pragma unroll
    for (int r = 0; r < 4; ++r) {
        t1[r] = acc[0][r] * aS[0] + acc[1][r] * aS[1] + acc[2][r] * aS[2] + acc[3][r] * aS[3];
        t2[r] = acc[0][r] * aD[0] + acc[1][r] * aD[1] + acc[2][r] * aD[2] + acc[3][r] * aD[3];
    }
#pragma unroll
    for (int off = 1; off <= 8; off <<= 1) {
#pragma unroll
        for (int r = 0; r < 4; ++r) {
            t1[r] += __shfl_xor(t1[r], off, 64);
            t2[r] += __shfl_xor(t2[r], off, 64);
        }
    }
    if (q == 0) {
#pragma unroll
        for (int r = 0; r < 4; ++r) {
            int rr = base + quad * 4 + r;
            int b = (rr >= N) ? 1 : 0;
            int n = rr - b * N;
            s1i[2 * n + b] = t1[r];
            s2i[2 * n + b] = t2[r];
        }
    }
}

// ---------------------------------------------------------------------------
// Histogram by dst + rank capture.
// ---------------------------------------------------------------------------
__global__ __launch_bounds__(256)
void k_hist(const int* __restrict__ e_dst, int* __restrict__ deg,
            int* __restrict__ rank, int E, int N)
{
    int e = blockIdx.x * 256 + threadIdx.x;
    if (e >= E) return;
    int d = e_dst[e];
    d = min(max(d, 0), N - 1);
    rank[e] = atomicAdd(deg + d, 1);
}

// ---------------------------------------------------------------------------
// Merged single-dispatch exclusive scan: block b sums deg[0..b*2048) for its
// own offset (redundant but trivial: <=200KB), then scans its 2048-chunk and
// writes rowptr. Last block writes rowptr[N]. Block-local only -> no races.
// ---------------------------------------------------------------------------
__global__ __launch_bounds__(256)
void k_scan(const int* __restrict__ deg, int* __restrict__ rowptr, int N, int nblk)
{
    __shared__ int wsum1[4], wsum2[4];
    __shared__ int s_pre;
    int t = threadIdx.x, lane = t & 63, wave = t >> 6;
    int b = blockIdx.x;

    // exclusive prefix over previous chunks
    int limit = b * 2048;
    int pacc = 0;
    for (int i = t; i < limit; i += 256) pacc += deg[i];
#pragma unroll
    for (int off = 32; off >= 1; off >>= 1) pacc += __shfl_xor(pacc, off, 64);
    if (lane == 0) wsum1[wave] = pacc;

    // own-chunk scan
    int base = b * 2048 + t * 8;
    int vals[8]; int s = 0;
#pragma unroll
    for (int j = 0; j < 8; ++j) {
        int i = base + j;
        vals[j] = (i < N) ? deg[i] : 0;
        s += vals[j];
    }
    int inc = s;
#pragma unroll
    for (int off = 1; off < 64; off <<= 1) {
        int u = __shfl_up(inc, off, 64);
        if (lane >= off) inc += u;
    }
    if (lane == 63) wsum2[wave] = inc;
    __syncthreads();

    if (t == 0) s_pre = wsum1[0] + wsum1[1] + wsum1[2] + wsum1[3];
    __syncthreads();

    int woff = 0;
#pragma unroll
    for (int w = 0; w < 4; ++w) if (w < wave) woff += wsum2[w];
    int running = s_pre + woff + (inc - s);
#pragma unroll
    for (int j = 0; j < 8; ++j) {
        int i = base + j;
        if (i < N) rowptr[i] = running;
        running += vals[j];
    }
    if (b == nblk - 1 && t == 0)
        rowptr[N] = s_pre + wsum2[0] + wsum2[1] + wsum2[2] + wsum2[3];
}

// ---------------------------------------------------------------------------
// Scatter (atomic-free): p = rowptr[d] + rank[e]; 8B record
// (src:u32, x0:bf16 | x1:bf16<<16). s1/s2 interleaved -> one float2 random
// read per endpoint.
// ---------------------------------------------------------------------------
__global__ __launch_bounds__(256)
void k_scatter(const int* __restrict__ e_src, const int* __restrict__ e_dst,
               const float2* __restrict__ s1i, const float2* __restrict__ s2i,
               const int* __restrict__ rowptr, const int* __restrict__ rank,
               uint2* __restrict__ rec, int E, int N)
{
    int e = blockIdx.x * 256 + threadIdx.x;
    if (e >= E) return;
    int d = e_dst[e];
    int s = e_src[e];
    d = min(max(d, 0), N - 1);
    s = min(max(s, 0), N - 1);
    int p = rowptr[d] + rank[e];
    float2 v1 = s1i[s];
    float2 v2 = s2i[d];
    float e0 = v1.x + v2.x;
    float e1 = v1.y + v2.y;
    e0 = e0 > 0.f ? e0 : ALPHA * e0;
    e1 = e1 > 0.f ? e1 : ALPHA * e1;
    unsigned u0 = bf16bits(__expf(e0));
    unsigned u1 = bf16bits(__expf(e1));
    rec[p] = make_uint2((unsigned)s, u0 | (u1 << 16));
}

// ---------------------------------------------------------------------------
// k_gather: one wave per dst. Lane = (g = edge slot 0..3, q = 0..15); q<8 ->
// batch0, q>=8 -> batch1. 8 edges/iter via 2 independent slots. Loop is
// layout-agnostic; epilogue maps the permuted chunks:
//   a[0]:col 2q', a[1]:16+2q', a[2]:32+2q', a[3]:48+2q',
//   a[4]:col 2q'+1, a[5]:16+2q'+1, a[6]:32+2q'+1, a[7]:48+2q'+1  (q' = q&7)
// -> 4 coalesced float2 stores per g==0 lane.
// ---------------------------------------------------------------------------
__global__ __launch_bounds__(256)
void k_gather(const int* __restrict__ rowptr, const uint2* __restrict__ rec,
              const unsigned int* __restrict__ Whb, float* __restrict__ out, int N)
{
    int lane = threadIdx.x & 63;
    int d = blockIdx.x * 4 + (threadIdx.x >> 6);
    if (d >= N) return;
    int g = lane >> 4, q = lane & 15;
    int b = q >> 3;

    int beg = rowptr[d];
    int end = rowptr[d + 1];
    const uint4* W = (const uint4*)Whb;   // 16 uint4 per node: [b0 x8][b1 x8]

    float a[8];
#pragma unroll
    for (int j = 0; j < 8; ++j) a[j] = 0.f;
    float nacc = 0.f;

    for (int i = beg; i < end; i += 8) {
        int e0 = i + g;
        int e1 = i + 4 + g;
        int ec0 = min(e0, end - 1);
        int ec1 = min(e1, end - 1);
        uint2 r0 = rec[ec0];
        uint2 r1 = rec[ec1];
        int s0 = (int)r0.x;
        int s1v = (int)r1.x;
        uint4 w0 = W[(size_t)s0 * 16 + q];
        uint4 w1 = W[(size_t)s1v * 16 + q];
        float x0 = (e0 < end) ? __uint_as_float(b ? (r0.y & 0xffff0000u) : (r0.y << 16)) : 0.f;
        float x1 = (e1 < end) ? __uint_as_float(b ? (r1.y & 0xffff0000u) : (r1.y << 16)) : 0.f;

        unsigned int u;
        u = w0.x; a[0] += x0 * __uint_as_float(u << 16); a[1] += x0 * __uint_as_float(u & 0xffff0000u);
        u = w0.y; a[2] += x0 * __uint_as_float(u << 16); a[3] += x0 * __uint_as_float(u & 0xffff0000u);
        u = w0.z; a[4] += x0 * __uint_as_float(u << 16); a[5] += x0 * __uint_as_float(u & 0xffff0000u);
        u = w0.w; a[6] += x0 * __uint_as_float(u << 16); a[7] += x0 * __uint_as_float(u & 0xffff0000u);
        u = w1.x; a[0] += x1 * __uint_as_float(u << 16); a[1] += x1 * __uint_as_float(u & 0xffff0000u);
        u = w1.y; a[2] += x1 * __uint_as_float(u << 16); a[3] += x1 * __uint_as_float(u & 0xffff0000u);
        u = w1.z; a[4] += x1 * __uint_as_float(u << 16); a[5] += x1 * __uint_as_float(u & 0xffff0000u);
        u = w1.w; a[6] += x1 * __uint_as_float(u << 16); a[7] += x1 * __uint_as_float(u & 0xffff0000u);
        nacc += x0 + x1;
    }

#pragma unroll
    for (int off = 16; off <= 32; off <<= 1) {
#pragma unroll
        for (int j = 0; j < 8; ++j) a[j] += __shfl_xor(a[j], off, 64);
        nacc += __shfl_xor(nacc, off, 64);
    }

    if (g == 0) {
        float inv = 1.f / (nacc + EPSV);
        float v[8];
#pragma unroll
        for (int j = 0; j < 8; ++j) {
            v[j] = a[j] * inv;
            v[j] = v[j] > 0.f ? v[j] : expm1f(v[j]);
        }
        float* orow = out + ((size_t)b * N + d) * OUTF;
        int c = (q & 7) * 2;
        *(float2*)(orow + c)      = make_float2(v[0], v[4]);
        *(float2*)(orow + 16 + c) = make_float2(v[1], v[5]);
        *(float2*)(orow + 32 + c) = make_float2(v[2], v[6]);
        *(float2*)(orow + 48 + c) = make_float2(v[3], v[7]);
    }
}

extern "C" void kernel_launch(void* const* d_in, const int* in_sizes, int n_in,
                              void* d_out, int out_size, void* d_ws, size_t ws_size,
                              hipStream_t stream)
{
    const float* h     = (const float*)d_in[0];
    const int*   ei    = (const int*)d_in[1];
    const float* Wfc   = (const float*)d_in[2];
    const float* Wattn = (const float*)d_in[3];
    float* out = (float*)d_out;

    int BN = in_sizes[0] / INF;     // B*N = 100000
    int N  = BN / 2;                // 50000
    int E  = in_sizes[1] / 2;       // 800000

    // ws: Whb[BN*64] bf16 | rec[E] u2 | s1i[BN] | s2i[BN] | deg[N] |
    //     rowptr[N+1] | rank[E] | WfcHi[8192] bf16 | WfcLo[8192] bf16
    __bf16* Whb    = (__bf16*)d_ws;
    uint2*  rec    = (uint2*)(Whb + (size_t)BN * OUTF);
    float*  s1i    = (float*)(rec + E);
    float*  s2i    = s1i + BN;
    int*    deg    = (int*)(s2i + BN);
    int*    rowptr = deg + N;
    int*    rank   = rowptr + N + 1;
    __bf16* WfcHi  = (__bf16*)(rank + E);
    __bf16* WfcLo  = WfcHi + OUTF * INF;

    int nblk = (N + 2047) / 2048;   // 25 for N=50000 (<=64 supported)

    k_prep0<<<(N + 255) / 256, 256, 0, stream>>>(Wfc, WfcHi, WfcLo, deg, N);
    k_fc<<<(BN / 16 + 3) / 4, 256, 0, stream>>>(h, WfcHi, WfcLo, Wattn,
                                                (uint2*)Whb, s1i, s2i, BN, N);
    k_hist<<<(E + 255) / 256, 256, 0, stream>>>(ei + E, deg, rank, E, N);
    k_scan<<<nblk, 256, 0, stream>>>(deg, rowptr, N, nblk);
    k_scatter<<<(E + 255) / 256, 256, 0, stream>>>(ei, ei + E, (const float2*)s1i,
                                                   (const float2*)s2i, rowptr, rank, rec, E, N);
    k_gather<<<(N + 3) / 4, 256, 0, stream>>>(rowptr, rec, (const unsigned int*)Whb, out, N);
}